// Round 5
// baseline (122874.695 us; speedup 1.0000x reference)
//
#include <hip/hip_runtime.h>
#include <cfloat>

// BruteForce top-K: B=512 x N=500000, D=128 fp32, K=100.
// (1) fp32 scoring + statistical filter t_q = 3.25*|q| (~289 survivors/query;
//     margin to true top-100 boundary ~11 std of the rank-100 order statistic).
// (2) fallback (only if cnt<K or cnt>cap): exact rescan keeping top-min(cap,256).
// (3) select: re-score survivors with a BIT-EXACT emulation of numpy's
//     einsum fp32 dot kernel (SSE-baseline universal SIMD: 4 strided lanes,
//     mul+add separately rounded, chunk chain a0b0+(a1b1+(a2b2+(a3b3+acc))),
//     SSE3 hadd reduce (s0+s1)+(s2+s3)), rank by (value desc, id asc)
//     == np stable argsort of -scores == the harness np reference.

#define D_DIM 128
#define K_TOP 100
#define QCH 16
#define THRESH_SIGMA 3.25f
#define CAP_MAX 1024
#define KEEP_MAXF 256

typedef float f32x16 __attribute__((ext_vector_type(16)));

__device__ __forceinline__ unsigned long long make_key(float v, unsigned id) {
    unsigned vb = __float_as_uint(v);
    unsigned vm = (vb & 0x80000000u) ? ~vb : (vb | 0x80000000u);  // monotone map
    return ((unsigned long long)vm << 32) | (0xFFFFFFFFu - id);   // val asc; id asc on tie
}

// ascending bitonic sort of S (pow2) u64 keys, blockDim.x threads
template <int S>
__device__ inline void bitonic_sort_u64(unsigned long long* buf) {
    for (int k = 2; k <= S; k <<= 1) {
        for (int j = k >> 1; j > 0; j >>= 1) {
            __syncthreads();
            for (int i = threadIdx.x; i < S; i += blockDim.x) {
                int l = i ^ j;
                if (l > i) {
                    unsigned long long a = buf[i], b = buf[l];
                    bool sw = ((i & k) == 0) ? (a > b) : (a < b);
                    if (sw) { buf[i] = b; buf[l] = a; }
                }
            }
        }
    }
    __syncthreads();
}

__global__ void prep_kernel(const float* __restrict__ Qm, float* __restrict__ qt,
                            int* __restrict__ cnt, int B) {
    int tid = blockIdx.x * blockDim.x + threadIdx.x;
    int total = B * D_DIM;
    if (tid < total) {
        int d = tid / B, b = tid - d * B;
        qt[(size_t)d * B + b] = Qm[(size_t)b * D_DIM + d];
    }
    if (tid < B) cnt[tid] = 0;
}

__global__ void thr_kernel(const float* __restrict__ Qm, float* __restrict__ thr, int B) {
    int b = blockIdx.x * blockDim.x + threadIdx.x;
    if (b < B) {
        float s = 0.f;
        for (int d = 0; d < D_DIM; ++d) { float v = Qm[(size_t)b * D_DIM + d]; s = fmaf(v, v, s); }
        thr[b] = THRESH_SIGMA * sqrtf(s);
    }
}

// fp32 scoring + filter: one candidate per lane (row in 128 VGPRs), queries
// broadcast via wave-uniform vector loads. Survivors: ids only.
__global__ __launch_bounds__(256, 2) void score_kernel(
    const float* __restrict__ cand, const float* __restrict__ qt,
    const float* __restrict__ thr, unsigned* __restrict__ idbuf,
    int* __restrict__ cnt, int N, int B, int cap) {
    const int cid = blockIdx.x * blockDim.x + threadIdx.x;
    const bool valid = (cid < N);
    const int crow = valid ? cid : 0;

    float creg[D_DIM];
    const float4* c4 = reinterpret_cast<const float4*>(cand + (size_t)crow * D_DIM);
#pragma unroll
    for (int i = 0; i < D_DIM / 4; ++i) {
        float4 v = c4[i];
        creg[4 * i + 0] = v.x; creg[4 * i + 1] = v.y;
        creg[4 * i + 2] = v.z; creg[4 * i + 3] = v.w;
    }

#pragma unroll 1
    for (int qb = 0; qb < B; qb += QCH) {
        float acc[QCH];
#pragma unroll
        for (int b = 0; b < QCH; ++b) acc[b] = 0.f;
#pragma unroll
        for (int d = 0; d < D_DIM; ++d) {
            f32x16 qv = *reinterpret_cast<const f32x16*>(qt + (size_t)d * B + qb);
#pragma unroll
            for (int b = 0; b < QCH; ++b) acc[b] = fmaf(qv[b], creg[d], acc[b]);
        }
        if (valid) {
            f32x16 tv = *reinterpret_cast<const f32x16*>(thr + qb);
#pragma unroll
            for (int b = 0; b < QCH; ++b) {
                if (acc[b] > tv[b]) {
                    int q = qb + b;
                    int pos = atomicAdd(&cnt[q], 1);
                    if (pos < cap) idbuf[(size_t)q * cap + pos] = (unsigned)cid;
                }
            }
        }
    }
}

// exact fallback: keeps top-keep (keep = min(cap,256)) by fp32
__global__ void fallback_kernel(const float* __restrict__ Qm, const float* __restrict__ cand,
                                unsigned* __restrict__ idbuf, int* __restrict__ cnt,
                                int N, int cap) {
    int q = blockIdx.x;
    int c0 = cnt[q];
    if (c0 >= K_TOP && c0 <= cap) return;
    int keep = (cap < KEEP_MAXF) ? cap : KEEP_MAXF;

    __shared__ unsigned long long buf[2048];
    __shared__ float qrow[D_DIM];
    __shared__ int bn;
    __shared__ float theta;
    __shared__ int validn;
    for (int i = threadIdx.x; i < D_DIM; i += blockDim.x) qrow[i] = Qm[(size_t)q * D_DIM + i];
    for (int i = threadIdx.x; i < 2048; i += blockDim.x) buf[i] = 0ULL;
    if (threadIdx.x == 0) { bn = 0; theta = -3.0e38f; }
    __syncthreads();

    for (int base = 0; base < N; base += blockDim.x) {
        int c = base + threadIdx.x;
        if (c < N) {
            float s = 0.f;
            for (int d = 0; d < D_DIM; ++d) s = fmaf(qrow[d], cand[(size_t)c * D_DIM + d], s);
            if (s > theta) {
                int p = atomicAdd(&bn, 1);
                if (p < 2048) buf[p] = make_key(s, (unsigned)c);
            }
        }
        __syncthreads();
        if (bn > 2048 - 256 - 8) {  // compress: keep top-keep, raise theta
            bitonic_sort_u64<2048>(buf);
            unsigned long long kv = (threadIdx.x < (unsigned)keep) ? buf[2047 - threadIdx.x] : 0ULL;
            __syncthreads();
            for (int i = threadIdx.x; i < 2048; i += blockDim.x) buf[i] = 0ULL;
            __syncthreads();
            if (threadIdx.x < (unsigned)keep) buf[threadIdx.x] = kv;
            if ((int)threadIdx.x == keep - 1) {
                unsigned vm = (unsigned)(kv >> 32);
                unsigned vb = (vm & 0x80000000u) ? (vm ^ 0x80000000u) : ~vm;
                theta = __uint_as_float(vb) - 0.01f;
            }
            if (threadIdx.x == 0) bn = keep;
            __syncthreads();
        }
    }
    bitonic_sort_u64<2048>(buf);
    if (threadIdx.x == 0) validn = 0;
    __syncthreads();
    unsigned long long kv = (threadIdx.x < (unsigned)keep) ? buf[2047 - threadIdx.x] : 0ULL;
    if (kv != 0ULL) atomicAdd(&validn, 1);
    __syncthreads();
    if ((int)threadIdx.x < validn && threadIdx.x < (unsigned)keep) {
        unsigned id = 0xFFFFFFFFu - (unsigned)(kv & 0xFFFFFFFFu);
        if (id < (unsigned)N) idbuf[(size_t)q * cap + threadIdx.x] = id;
    }
    if (threadIdx.x == 0) cnt[q] = (validn < keep) ? validn : keep;
}

// --- bit-exact emulation of numpy einsum fp32 dot (SSE baseline, no FMA) ---
__device__ __forceinline__ float np_lane_chain(float q0, float b0v, float q1, float b1v,
                                               float q2, float b2v, float q3, float b3v,
                                               float acc) {
    // ab3 = a3*b3 + acc; ab2 = a2*b2 + ab3; ab1 = a1*b1 + ab2; acc = a0*b0 + ab1
    float t = __fadd_rn(__fmul_rn(q3, b3v), acc);
    t = __fadd_rn(__fmul_rn(q2, b2v), t);
    t = __fadd_rn(__fmul_rn(q1, b1v), t);
    return __fadd_rn(__fmul_rn(q0, b0v), t);
}

__device__ __forceinline__ float np_score(const float* __restrict__ qrow,
                                          const float* __restrict__ crow) {
    float acc0 = 0.f, acc1 = 0.f, acc2 = 0.f, acc3 = 0.f;
#pragma unroll
    for (int d0 = 0; d0 < D_DIM; d0 += 16) {
        float4 b0 = *reinterpret_cast<const float4*>(crow + d0 + 0);
        float4 b1 = *reinterpret_cast<const float4*>(crow + d0 + 4);
        float4 b2 = *reinterpret_cast<const float4*>(crow + d0 + 8);
        float4 b3 = *reinterpret_cast<const float4*>(crow + d0 + 12);
        acc0 = np_lane_chain(qrow[d0 + 0], b0.x, qrow[d0 + 4], b1.x,
                             qrow[d0 + 8], b2.x, qrow[d0 + 12], b3.x, acc0);
        acc1 = np_lane_chain(qrow[d0 + 1], b0.y, qrow[d0 + 5], b1.y,
                             qrow[d0 + 9], b2.y, qrow[d0 + 13], b3.y, acc1);
        acc2 = np_lane_chain(qrow[d0 + 2], b0.z, qrow[d0 + 6], b1.z,
                             qrow[d0 + 10], b2.z, qrow[d0 + 14], b3.z, acc2);
        acc3 = np_lane_chain(qrow[d0 + 3], b0.w, qrow[d0 + 7], b1.w,
                             qrow[d0 + 11], b2.w, qrow[d0 + 15], b3.w, acc3);
    }
    // SSE3 hadd reduce: (s0+s1) + (s2+s3)
    return __fadd_rn(__fadd_rn(acc0, acc1), __fadd_rn(acc2, acc3));
}

// selection: numpy-exact fp32 re-score, rank by (value desc, id asc)
__global__ __launch_bounds__(256) void select_kernel(
    const float* __restrict__ Qm, const float* __restrict__ cand,
    const unsigned* __restrict__ idbuf, const int* __restrict__ cnt,
    const int* __restrict__ ident, float* __restrict__ out, int N, int B, int cap) {
    __shared__ unsigned long long skey[CAP_MAX];
    __shared__ float qrow[D_DIM];
    int q = blockIdx.x;
    for (int i = threadIdx.x; i < D_DIM; i += blockDim.x) qrow[i] = Qm[(size_t)q * D_DIM + i];
    __syncthreads();

    int n = cnt[q]; if (n > cap) n = cap; if (n > CAP_MAX) n = CAP_MAX;
    for (int i = threadIdx.x; i < CAP_MAX; i += blockDim.x) {
        unsigned long long key = 0ULL;
        if (i < n) {
            unsigned id = idbuf[(size_t)q * cap + i];
            if (id < (unsigned)N) {
                float s = np_score(qrow, cand + (size_t)id * D_DIM);
                key = make_key(s, id);
            }
        }
        skey[i] = key;
    }

    bitonic_sort_u64<CAP_MAX>(skey);   // ascending: best at the end

    for (int t = threadIdx.x; t < K_TOP; t += blockDim.x) {
        unsigned long long key = skey[CAP_MAX - 1 - t];
        unsigned vm = (unsigned)(key >> 32);
        unsigned vb = (vm & 0x80000000u) ? (vm ^ 0x80000000u) : ~vm;
        unsigned id = 0xFFFFFFFFu - (unsigned)(key & 0xFFFFFFFFu);
        if (id >= (unsigned)N) id = 0;  // unreachable pad guard
        out[(size_t)q * K_TOP + t] = __uint_as_float(vb);
        out[(size_t)B * K_TOP + (size_t)q * K_TOP + t] = (float)ident[id];
    }
}

extern "C" void kernel_launch(void* const* d_in, const int* in_sizes, int n_in,
                              void* d_out, int out_size, void* d_ws, size_t ws_size,
                              hipStream_t stream) {
    const float* queries = (const float*)d_in[0];
    const float* cands   = (const float*)d_in[1];
    const int*   ident   = (const int*)d_in[2];
    const int B = in_sizes[0] / D_DIM;   // 512
    const int N = in_sizes[2];           // 500000
    float* out = (float*)d_out;

    char* ws = (char*)d_ws;
    int*   cnt = (int*)ws;                         // B ints
    float* thr = (float*)(ws + 2048);              // B floats
    float* qt  = (float*)(ws + 4096);              // D*B floats (d-major)
    size_t ids_off = 4096 + (size_t)B * D_DIM * 4; // 266240 for B=512
    unsigned* idbuf = (unsigned*)(ws + ids_off);
    int cap = CAP_MAX;
    if (ws_size > ids_off) {
        size_t fit = (ws_size - ids_off) / ((size_t)B * 4);
        if (fit < (size_t)cap) cap = (int)fit;
    } else cap = 1;
    if (cap < 1) cap = 1;

    int prep_blocks = (B * D_DIM + 255) / 256;
    prep_kernel<<<prep_blocks, 256, 0, stream>>>(queries, qt, cnt, B);
    thr_kernel<<<(B + 255) / 256, 256, 0, stream>>>(queries, thr, B);

    int score_blocks = (N + 255) / 256;
    score_kernel<<<score_blocks, 256, 0, stream>>>(cands, qt, thr, idbuf, cnt, N, B, cap);

    fallback_kernel<<<B, 256, 0, stream>>>(queries, cands, idbuf, cnt, N, cap);

    select_kernel<<<B, 256, 0, stream>>>(queries, cands, idbuf, cnt, ident, out, N, B, cap);
}

// Round 6
// 811.344 us; speedup vs baseline: 151.4459x; 151.4459x over previous
//
#include <hip/hip_runtime.h>
#include <cfloat>

// BruteForce top-K: B=512 x N=500000, D=128 fp32, K=100.
// (1) fp32 vector-GEMM scoring (LDS-tiled, 8x8 register blocking -- no
//     per-thread giant arrays, no scratch spill) fused with statistical
//     filter t_q = 3.25*|q| (~289 survivors/query; margin to true top-100
//     boundary ~11 std of the rank-100 order statistic).
// (2) fallback (only if cnt<K or cnt>cap): exact rescan keeping top-min(cap,256).
// (3) select: re-score survivors with a BIT-EXACT emulation of numpy's
//     einsum fp32 dot kernel (SSE-baseline: 4 strided lanes, mul+add
//     separately rounded, chunk chain a0b0+(a1b1+(a2b2+(a3b3+acc))),
//     hadd reduce (s0+s1)+(s2+s3)), rank by (value desc, id asc).

#define D_DIM 128
#define K_TOP 100
#define THRESH_SIGMA 3.25f
#define CAP_MAX 1024
#define KEEP_MAXF 256

#define BM 128   // candidates per block tile
#define BN 128   // queries per block tile
#define BK 16    // k-chunk
#define RM 8     // candidates per thread
#define RN 8     // queries per thread

__device__ __forceinline__ unsigned long long make_key(float v, unsigned id) {
    unsigned vb = __float_as_uint(v);
    unsigned vm = (vb & 0x80000000u) ? ~vb : (vb | 0x80000000u);  // monotone map
    return ((unsigned long long)vm << 32) | (0xFFFFFFFFu - id);   // val asc; id asc on tie
}

template <int S>
__device__ inline void bitonic_sort_u64(unsigned long long* buf) {
    for (int k = 2; k <= S; k <<= 1) {
        for (int j = k >> 1; j > 0; j >>= 1) {
            __syncthreads();
            for (int i = threadIdx.x; i < S; i += blockDim.x) {
                int l = i ^ j;
                if (l > i) {
                    unsigned long long a = buf[i], b = buf[l];
                    bool sw = ((i & k) == 0) ? (a > b) : (a < b);
                    if (sw) { buf[i] = b; buf[l] = a; }
                }
            }
        }
    }
    __syncthreads();
}

// per-query threshold + counter zero
__global__ void thr_kernel(const float* __restrict__ Qm, float* __restrict__ thr,
                           int* __restrict__ cnt, int B) {
    int b = blockIdx.x * blockDim.x + threadIdx.x;
    if (b < B) {
        float s = 0.f;
        for (int d = 0; d < D_DIM; ++d) { float v = Qm[(size_t)b * D_DIM + d]; s = fmaf(v, v, s); }
        thr[b] = THRESH_SIGMA * sqrtf(s);
        cnt[b] = 0;
    }
}

// fp32 tiled GEMM + threshold filter. acc 8x8 per thread (64 VGPR), LDS
// tiles [BK][128+4] (16B-aligned rows -> ds_read_b128 fragments).
__global__ __launch_bounds__(256) void gemm_filter_kernel(
    const float* __restrict__ cand, const float* __restrict__ Qm,
    const float* __restrict__ thr, unsigned* __restrict__ idbuf,
    int* __restrict__ cnt, int N, int B, int cap) {
    __shared__ float ct[BK][BM + 4];
    __shared__ float qt[BK][BN + 4];

    const int c_base = blockIdx.x * BM;
    const int q_base = blockIdx.y * BN;
    const int t = threadIdx.x;
    const int tx = t & 15;        // candidate group: cands tx*8 .. tx*8+7
    const int ty = t >> 4;        // query group:     queries ty*8 .. ty*8+7

    float acc[RM][RN];
#pragma unroll
    for (int i = 0; i < RM; ++i)
#pragma unroll
        for (int j = 0; j < RN; ++j) acc[i][j] = 0.f;

    const int f4  = t & 3;        // float4 column within BK chunk
    const int row0 = t >> 2;      // 0..63

#pragma unroll 1
    for (int kt = 0; kt < D_DIM; kt += BK) {
        __syncthreads();
        // stage candidate tile: BM rows x BK dims, transposed into ct[k][c]
#pragma unroll
        for (int rr = 0; rr < 2; ++rr) {
            int row = row0 + rr * 64;
            int gc = c_base + row;
            float4 v = make_float4(0.f, 0.f, 0.f, 0.f);
            if (gc < N)
                v = *reinterpret_cast<const float4*>(cand + (size_t)gc * D_DIM + kt + f4 * 4);
            ct[f4 * 4 + 0][row] = v.x;
            ct[f4 * 4 + 1][row] = v.y;
            ct[f4 * 4 + 2][row] = v.z;
            ct[f4 * 4 + 3][row] = v.w;
        }
        // stage query tile: BN rows x BK dims, transposed into qt[k][q]
#pragma unroll
        for (int rr = 0; rr < 2; ++rr) {
            int row = row0 + rr * 64;
            int gq = q_base + row;
            float4 v = make_float4(0.f, 0.f, 0.f, 0.f);
            if (gq < B)
                v = *reinterpret_cast<const float4*>(Qm + (size_t)gq * D_DIM + kt + f4 * 4);
            qt[f4 * 4 + 0][row] = v.x;
            qt[f4 * 4 + 1][row] = v.y;
            qt[f4 * 4 + 2][row] = v.z;
            qt[f4 * 4 + 3][row] = v.w;
        }
        __syncthreads();

#pragma unroll
        for (int kk = 0; kk < BK; ++kk) {
            float4 ca = *reinterpret_cast<const float4*>(&ct[kk][tx * 8]);
            float4 cb = *reinterpret_cast<const float4*>(&ct[kk][tx * 8 + 4]);
            float4 qa = *reinterpret_cast<const float4*>(&qt[kk][ty * 8]);
            float4 qb = *reinterpret_cast<const float4*>(&qt[kk][ty * 8 + 4]);
            float cf[RM] = {ca.x, ca.y, ca.z, ca.w, cb.x, cb.y, cb.z, cb.w};
            float qf[RN] = {qa.x, qa.y, qa.z, qa.w, qb.x, qb.y, qb.z, qb.w};
#pragma unroll
            for (int i = 0; i < RM; ++i)
#pragma unroll
                for (int j = 0; j < RN; ++j) acc[i][j] = fmaf(cf[i], qf[j], acc[i][j]);
        }
    }

    // filter epilogue: push survivor ids
#pragma unroll
    for (int j = 0; j < RN; ++j) {
        int tq = q_base + ty * 8 + j;
        if (tq >= B) continue;
        float tv = thr[tq];
#pragma unroll
        for (int i = 0; i < RM; ++i) {
            int gc = c_base + tx * 8 + i;
            if (gc < N && acc[i][j] > tv) {
                int pos = atomicAdd(&cnt[tq], 1);
                if (pos < cap) idbuf[(size_t)tq * cap + pos] = (unsigned)gc;
            }
        }
    }
}

// exact fallback: keeps top-keep (keep = min(cap,256)) by fp32
__global__ void fallback_kernel(const float* __restrict__ Qm, const float* __restrict__ cand,
                                unsigned* __restrict__ idbuf, int* __restrict__ cnt,
                                int N, int cap) {
    int q = blockIdx.x;
    int c0 = cnt[q];
    if (c0 >= K_TOP && c0 <= cap) return;
    int keep = (cap < KEEP_MAXF) ? cap : KEEP_MAXF;

    __shared__ unsigned long long buf[2048];
    __shared__ float qrow[D_DIM];
    __shared__ int bn;
    __shared__ float theta;
    __shared__ int validn;
    for (int i = threadIdx.x; i < D_DIM; i += blockDim.x) qrow[i] = Qm[(size_t)q * D_DIM + i];
    for (int i = threadIdx.x; i < 2048; i += blockDim.x) buf[i] = 0ULL;
    if (threadIdx.x == 0) { bn = 0; theta = -3.0e38f; }
    __syncthreads();

    for (int base = 0; base < N; base += blockDim.x) {
        int c = base + threadIdx.x;
        if (c < N) {
            float s = 0.f;
            for (int d = 0; d < D_DIM; ++d) s = fmaf(qrow[d], cand[(size_t)c * D_DIM + d], s);
            if (s > theta) {
                int p = atomicAdd(&bn, 1);
                if (p < 2048) buf[p] = make_key(s, (unsigned)c);
            }
        }
        __syncthreads();
        if (bn > 2048 - 256 - 8) {  // compress: keep top-keep, raise theta
            bitonic_sort_u64<2048>(buf);
            unsigned long long kv = (threadIdx.x < (unsigned)keep) ? buf[2047 - threadIdx.x] : 0ULL;
            __syncthreads();
            for (int i = threadIdx.x; i < 2048; i += blockDim.x) buf[i] = 0ULL;
            __syncthreads();
            if (threadIdx.x < (unsigned)keep) buf[threadIdx.x] = kv;
            if ((int)threadIdx.x == keep - 1) {
                unsigned vm = (unsigned)(kv >> 32);
                unsigned vb = (vm & 0x80000000u) ? (vm ^ 0x80000000u) : ~vm;
                theta = __uint_as_float(vb) - 0.01f;
            }
            if (threadIdx.x == 0) bn = keep;
            __syncthreads();
        }
    }
    bitonic_sort_u64<2048>(buf);
    if (threadIdx.x == 0) validn = 0;
    __syncthreads();
    unsigned long long kv = (threadIdx.x < (unsigned)keep) ? buf[2047 - threadIdx.x] : 0ULL;
    if (kv != 0ULL) atomicAdd(&validn, 1);
    __syncthreads();
    if ((int)threadIdx.x < validn && threadIdx.x < (unsigned)keep) {
        unsigned id = 0xFFFFFFFFu - (unsigned)(kv & 0xFFFFFFFFu);
        if (id < (unsigned)N) idbuf[(size_t)q * cap + threadIdx.x] = id;
    }
    if (threadIdx.x == 0) cnt[q] = (validn < keep) ? validn : keep;
}

// --- bit-exact emulation of numpy einsum fp32 dot (SSE baseline, no FMA) ---
__device__ __forceinline__ float np_lane_chain(float q0, float b0v, float q1, float b1v,
                                               float q2, float b2v, float q3, float b3v,
                                               float acc) {
    float t = __fadd_rn(__fmul_rn(q3, b3v), acc);
    t = __fadd_rn(__fmul_rn(q2, b2v), t);
    t = __fadd_rn(__fmul_rn(q1, b1v), t);
    return __fadd_rn(__fmul_rn(q0, b0v), t);
}

__device__ __forceinline__ float np_score(const float* __restrict__ qrow,
                                          const float* __restrict__ crow) {
    float acc0 = 0.f, acc1 = 0.f, acc2 = 0.f, acc3 = 0.f;
#pragma unroll
    for (int d0 = 0; d0 < D_DIM; d0 += 16) {
        float4 b0 = *reinterpret_cast<const float4*>(crow + d0 + 0);
        float4 b1 = *reinterpret_cast<const float4*>(crow + d0 + 4);
        float4 b2 = *reinterpret_cast<const float4*>(crow + d0 + 8);
        float4 b3 = *reinterpret_cast<const float4*>(crow + d0 + 12);
        acc0 = np_lane_chain(qrow[d0 + 0], b0.x, qrow[d0 + 4], b1.x,
                             qrow[d0 + 8], b2.x, qrow[d0 + 12], b3.x, acc0);
        acc1 = np_lane_chain(qrow[d0 + 1], b0.y, qrow[d0 + 5], b1.y,
                             qrow[d0 + 9], b2.y, qrow[d0 + 13], b3.y, acc1);
        acc2 = np_lane_chain(qrow[d0 + 2], b0.z, qrow[d0 + 6], b1.z,
                             qrow[d0 + 10], b2.z, qrow[d0 + 14], b3.z, acc2);
        acc3 = np_lane_chain(qrow[d0 + 3], b0.w, qrow[d0 + 7], b1.w,
                             qrow[d0 + 11], b2.w, qrow[d0 + 15], b3.w, acc3);
    }
    return __fadd_rn(__fadd_rn(acc0, acc1), __fadd_rn(acc2, acc3));
}

// selection: numpy-exact fp32 re-score, rank by (value desc, id asc)
__global__ __launch_bounds__(256) void select_kernel(
    const float* __restrict__ Qm, const float* __restrict__ cand,
    const unsigned* __restrict__ idbuf, const int* __restrict__ cnt,
    const int* __restrict__ ident, float* __restrict__ out, int N, int B, int cap) {
    __shared__ unsigned long long skey[CAP_MAX];
    __shared__ float qrow[D_DIM];
    int q = blockIdx.x;
    for (int i = threadIdx.x; i < D_DIM; i += blockDim.x) qrow[i] = Qm[(size_t)q * D_DIM + i];
    __syncthreads();

    int n = cnt[q]; if (n > cap) n = cap; if (n > CAP_MAX) n = CAP_MAX;
    for (int i = threadIdx.x; i < CAP_MAX; i += blockDim.x) {
        unsigned long long key = 0ULL;
        if (i < n) {
            unsigned id = idbuf[(size_t)q * cap + i];
            if (id < (unsigned)N) {
                float s = np_score(qrow, cand + (size_t)id * D_DIM);
                key = make_key(s, id);
            }
        }
        skey[i] = key;
    }

    bitonic_sort_u64<CAP_MAX>(skey);   // ascending: best at the end

    for (int t = threadIdx.x; t < K_TOP; t += blockDim.x) {
        unsigned long long key = skey[CAP_MAX - 1 - t];
        unsigned vm = (unsigned)(key >> 32);
        unsigned vb = (vm & 0x80000000u) ? (vm ^ 0x80000000u) : ~vm;
        unsigned id = 0xFFFFFFFFu - (unsigned)(key & 0xFFFFFFFFu);
        if (id >= (unsigned)N) id = 0;  // unreachable pad guard
        out[(size_t)q * K_TOP + t] = __uint_as_float(vb);
        out[(size_t)B * K_TOP + (size_t)q * K_TOP + t] = (float)ident[id];
    }
}

extern "C" void kernel_launch(void* const* d_in, const int* in_sizes, int n_in,
                              void* d_out, int out_size, void* d_ws, size_t ws_size,
                              hipStream_t stream) {
    const float* queries = (const float*)d_in[0];
    const float* cands   = (const float*)d_in[1];
    const int*   ident   = (const int*)d_in[2];
    const int B = in_sizes[0] / D_DIM;   // 512
    const int N = in_sizes[2];           // 500000
    float* out = (float*)d_out;

    char* ws = (char*)d_ws;
    int*   cnt = (int*)ws;                         // B ints
    float* thr = (float*)(ws + 2048);              // B floats
    size_t ids_off = 4096;
    unsigned* idbuf = (unsigned*)(ws + ids_off);
    int cap = CAP_MAX;
    if (ws_size > ids_off) {
        size_t fit = (ws_size - ids_off) / ((size_t)B * 4);
        if (fit < (size_t)cap) cap = (int)fit;
    } else cap = 1;
    if (cap < 1) cap = 1;

    thr_kernel<<<(B + 255) / 256, 256, 0, stream>>>(queries, thr, cnt, B);

    dim3 grid((N + BM - 1) / BM, (B + BN - 1) / BN);
    gemm_filter_kernel<<<grid, 256, 0, stream>>>(cands, queries, thr, idbuf, cnt, N, B, cap);

    fallback_kernel<<<B, 256, 0, stream>>>(queries, cands, idbuf, cnt, N, cap);

    select_kernel<<<B, 256, 0, stream>>>(queries, cands, idbuf, cnt, ident, out, N, B, cap);
}

// Round 8
// 335.618 us; speedup vs baseline: 366.1149x; 2.4175x over previous
//
#include <hip/hip_runtime.h>
#include <cfloat>

// BruteForce top-K: B=512 x N=500000, D=128 fp32, K=100.
// (1) bf16 MFMA GEMM scoring (16x16x32, LDS XOR-swizzled tiles, in-register
//     fp32->bf16 cvt) fused with statistical filter t_q = 3.25*|q|
//     (~289 survivors/query; bf16 score noise ~0.03 << 3.3 margin to the
//     true top-100 boundary -> survivor superset w.p. ~1).
// (2) fallback (only if cnt<K or cnt>cap): exact fp32 rescan keeping top-min(cap,256).
// (3) select: re-score survivors with a BIT-EXACT emulation of numpy's
//     einsum fp32 dot kernel, rank by (value desc, id asc). Exact output.

#define D_DIM 128
#define K_TOP 100
#define THRESH_SIGMA 3.25f
#define CAP_MAX 1024
#define KEEP_MAXF 256

typedef short bf16x8 __attribute__((ext_vector_type(8)));
typedef float f32x4 __attribute__((ext_vector_type(4)));

__device__ __forceinline__ unsigned short f2bf(float x) {  // RNE fp32->bf16
    unsigned u = __float_as_uint(x);
    return (unsigned short)((u + 0x7FFFu + ((u >> 16) & 1u)) >> 16);
}

__device__ __forceinline__ unsigned long long make_key(float v, unsigned id) {
    unsigned vb = __float_as_uint(v);
    unsigned vm = (vb & 0x80000000u) ? ~vb : (vb | 0x80000000u);  // monotone map
    return ((unsigned long long)vm << 32) | (0xFFFFFFFFu - id);   // val asc; id asc on tie
}

template <int S>
__device__ inline void bitonic_sort_u64(unsigned long long* buf) {
    for (int k = 2; k <= S; k <<= 1) {
        for (int j = k >> 1; j > 0; j >>= 1) {
            __syncthreads();
            for (int i = threadIdx.x; i < S; i += blockDim.x) {
                int l = i ^ j;
                if (l > i) {
                    unsigned long long a = buf[i], b = buf[l];
                    bool sw = ((i & k) == 0) ? (a > b) : (a < b);
                    if (sw) { buf[i] = b; buf[l] = a; }
                }
            }
        }
    }
    __syncthreads();
}

// threshold + counter zero + query fp32->bf16 conversion
__global__ void prep2_kernel(const float* __restrict__ Qm, float* __restrict__ thr,
                             int* __restrict__ cnt, unsigned short* __restrict__ qb16, int B) {
    int b = blockIdx.x * blockDim.x + threadIdx.x;
    if (b >= B) return;
    float s = 0.f;
    for (int d = 0; d < D_DIM; ++d) {
        float v = Qm[(size_t)b * D_DIM + d];
        s = fmaf(v, v, s);
        qb16[(size_t)b * D_DIM + d] = f2bf(v);
    }
    thr[b] = THRESH_SIGMA * sqrtf(s);
    cnt[b] = 0;
}

// bf16 MFMA GEMM + threshold filter.
// Block: 256 thr = 4 waves; tile 128 cand x 128 queries/chunk, K=128 full.
// Wave w owns cands w*32..w*32+31 (2 frag-rows); 8 query frag-cols.
// LDS: [128][128] bf16 tiles (256 B rows), byte-offset XOR swizzle ((row&7)<<4).
__global__ __launch_bounds__(256) void mfma_filter_kernel(
    const float* __restrict__ cand, const unsigned short* __restrict__ qb16,
    const float* __restrict__ thr, unsigned* __restrict__ idbuf,
    int* __restrict__ cnt, int N, int B, int cap) {
    __shared__ char cl[32768];
    __shared__ char ql[32768];
    const int t = threadIdx.x;
    const int w = t >> 6;
    const int l = t & 63;
    const int c0 = blockIdx.x * 128;

    // stage candidate tile: 128 rows x 128 f32 -> bf16, swizzled
#pragma unroll
    for (int i = 0; i < 16; ++i) {
        int f4 = i * 256 + t;        // flat float4 index, 4096 total
        int row = f4 >> 5;           // 32 float4 per row (128 floats)
        int colf4 = f4 & 31;
        int gc = c0 + row;
        float4 v = make_float4(0.f, 0.f, 0.f, 0.f);
        if (gc < N) v = *reinterpret_cast<const float4*>(cand + (size_t)gc * D_DIM + colf4 * 4);
        uint2 pk;
        pk.x = (unsigned)f2bf(v.x) | ((unsigned)f2bf(v.y) << 16);
        pk.y = (unsigned)f2bf(v.z) | ((unsigned)f2bf(v.w) << 16);
        int byte = row * 256 + ((colf4 * 8) ^ ((row & 7) << 4));
        *reinterpret_cast<uint2*>(cl + byte) = pk;
    }

    const int nch = (B + 127) >> 7;
#pragma unroll 1
    for (int qch = 0; qch < nch; ++qch) {
        __syncthreads();
        // stage query chunk (pre-converted bf16), swizzled
#pragma unroll
        for (int i = 0; i < 16; ++i) {
            int u2 = i * 256 + t;    // flat uint2 index, 4096 total
            int row = u2 >> 5;       // 32 uint2 per row (256 B)
            int col8 = u2 & 31;
            uint2 pk = reinterpret_cast<const uint2*>(qb16)[(size_t)qch * 4096 + u2];
            int byte = row * 256 + ((col8 * 8) ^ ((row & 7) << 4));
            *reinterpret_cast<uint2*>(ql + byte) = pk;
        }
        __syncthreads();

        // A fragments (cands), reused across all 8 query blocks
        bf16x8 af[2][4];
#pragma unroll
        for (int cb = 0; cb < 2; ++cb) {
            int row = w * 32 + cb * 16 + (l & 15);
            int sw = (row & 7) << 4;
#pragma unroll
            for (int ks = 0; ks < 4; ++ks) {
                int byte = row * 256 + ((ks * 64 + ((l >> 4) * 16)) ^ sw);
                af[cb][ks] = *reinterpret_cast<const bf16x8*>(cl + byte);
            }
        }

        f32x4 acc[2][8];
#pragma unroll
        for (int cb = 0; cb < 2; ++cb)
#pragma unroll
            for (int qb = 0; qb < 8; ++qb) acc[cb][qb] = (f32x4){0.f, 0.f, 0.f, 0.f};

#pragma unroll
        for (int qb = 0; qb < 8; ++qb) {
            int row = qb * 16 + (l & 15);
            int sw = (row & 7) << 4;
            bf16x8 bq[4];
#pragma unroll
            for (int ks = 0; ks < 4; ++ks) {
                int byte = row * 256 + ((ks * 64 + ((l >> 4) * 16)) ^ sw);
                bq[ks] = *reinterpret_cast<const bf16x8*>(ql + byte);
            }
#pragma unroll
            for (int cb = 0; cb < 2; ++cb)
#pragma unroll
                for (int ks = 0; ks < 4; ++ks)
                    acc[cb][qb] = __builtin_amdgcn_mfma_f32_16x16x32_bf16(
                        af[cb][ks], bq[ks], acc[cb][qb], 0, 0, 0);
        }

        // filter epilogue: D layout col=lane&15 (query), row=(lane>>4)*4+reg (cand)
#pragma unroll
        for (int qb = 0; qb < 8; ++qb) {
            int qg = qch * 128 + qb * 16 + (l & 15);
            if (qg >= B) continue;
            float tv = thr[qg];
#pragma unroll
            for (int cb = 0; cb < 2; ++cb) {
#pragma unroll
                for (int r = 0; r < 4; ++r) {
                    float s = acc[cb][qb][r];
                    if (s > tv) {
                        int cid = c0 + w * 32 + cb * 16 + ((l >> 4) << 2) + r;
                        if (cid < N) {
                            int pos = atomicAdd(&cnt[qg], 1);
                            if (pos < cap) idbuf[(size_t)qg * cap + pos] = (unsigned)cid;
                        }
                    }
                }
            }
        }
    }
}

// exact fallback: keeps top-keep (keep = min(cap,256)) by fp32
__global__ void fallback_kernel(const float* __restrict__ Qm, const float* __restrict__ cand,
                                unsigned* __restrict__ idbuf, int* __restrict__ cnt,
                                int N, int cap) {
    int q = blockIdx.x;
    int c0 = cnt[q];
    if (c0 >= K_TOP && c0 <= cap) return;
    int keep = (cap < KEEP_MAXF) ? cap : KEEP_MAXF;

    __shared__ unsigned long long buf[2048];
    __shared__ float qrow[D_DIM];
    __shared__ int bn;
    __shared__ float theta;
    __shared__ int validn;
    for (int i = threadIdx.x; i < D_DIM; i += blockDim.x) qrow[i] = Qm[(size_t)q * D_DIM + i];
    for (int i = threadIdx.x; i < 2048; i += blockDim.x) buf[i] = 0ULL;
    if (threadIdx.x == 0) { bn = 0; theta = -3.0e38f; }
    __syncthreads();

    for (int base = 0; base < N; base += blockDim.x) {
        int c = base + threadIdx.x;
        if (c < N) {
            float s = 0.f;
            for (int d = 0; d < D_DIM; ++d) s = fmaf(qrow[d], cand[(size_t)c * D_DIM + d], s);
            if (s > theta) {
                int p = atomicAdd(&bn, 1);
                if (p < 2048) buf[p] = make_key(s, (unsigned)c);
            }
        }
        __syncthreads();
        if (bn > 2048 - 256 - 8) {  // compress: keep top-keep, raise theta
            bitonic_sort_u64<2048>(buf);
            unsigned long long kv = (threadIdx.x < (unsigned)keep) ? buf[2047 - threadIdx.x] : 0ULL;
            __syncthreads();
            for (int i = threadIdx.x; i < 2048; i += blockDim.x) buf[i] = 0ULL;
            __syncthreads();
            if (threadIdx.x < (unsigned)keep) buf[threadIdx.x] = kv;
            if ((int)threadIdx.x == keep - 1) {
                unsigned vm = (unsigned)(kv >> 32);
                unsigned vb = (vm & 0x80000000u) ? (vm ^ 0x80000000u) : ~vm;
                theta = __uint_as_float(vb) - 0.01f;
            }
            if (threadIdx.x == 0) bn = keep;
            __syncthreads();
        }
    }
    bitonic_sort_u64<2048>(buf);
    if (threadIdx.x == 0) validn = 0;
    __syncthreads();
    unsigned long long kv = (threadIdx.x < (unsigned)keep) ? buf[2047 - threadIdx.x] : 0ULL;
    if (kv != 0ULL) atomicAdd(&validn, 1);
    __syncthreads();
    if ((int)threadIdx.x < validn && threadIdx.x < (unsigned)keep) {
        unsigned id = 0xFFFFFFFFu - (unsigned)(kv & 0xFFFFFFFFu);
        if (id < (unsigned)N) idbuf[(size_t)q * cap + threadIdx.x] = id;
    }
    if (threadIdx.x == 0) cnt[q] = (validn < keep) ? validn : keep;
}

// --- bit-exact emulation of numpy einsum fp32 dot (SSE baseline, no FMA) ---
__device__ __forceinline__ float np_lane_chain(float q0, float b0v, float q1, float b1v,
                                               float q2, float b2v, float q3, float b3v,
                                               float acc) {
    float t = __fadd_rn(__fmul_rn(q3, b3v), acc);
    t = __fadd_rn(__fmul_rn(q2, b2v), t);
    t = __fadd_rn(__fmul_rn(q1, b1v), t);
    return __fadd_rn(__fmul_rn(q0, b0v), t);
}

__device__ __forceinline__ float np_score(const float* __restrict__ qrow,
                                          const float* __restrict__ crow) {
    float acc0 = 0.f, acc1 = 0.f, acc2 = 0.f, acc3 = 0.f;
#pragma unroll
    for (int d0 = 0; d0 < D_DIM; d0 += 16) {
        float4 b0 = *reinterpret_cast<const float4*>(crow + d0 + 0);
        float4 b1 = *reinterpret_cast<const float4*>(crow + d0 + 4);
        float4 b2 = *reinterpret_cast<const float4*>(crow + d0 + 8);
        float4 b3 = *reinterpret_cast<const float4*>(crow + d0 + 12);
        acc0 = np_lane_chain(qrow[d0 + 0], b0.x, qrow[d0 + 4], b1.x,
                             qrow[d0 + 8], b2.x, qrow[d0 + 12], b3.x, acc0);
        acc1 = np_lane_chain(qrow[d0 + 1], b0.y, qrow[d0 + 5], b1.y,
                             qrow[d0 + 9], b2.y, qrow[d0 + 13], b3.y, acc1);
        acc2 = np_lane_chain(qrow[d0 + 2], b0.z, qrow[d0 + 6], b1.z,
                             qrow[d0 + 10], b2.z, qrow[d0 + 14], b3.z, acc2);
        acc3 = np_lane_chain(qrow[d0 + 3], b0.w, qrow[d0 + 7], b1.w,
                             qrow[d0 + 11], b2.w, qrow[d0 + 15], b3.w, acc3);
    }
    return __fadd_rn(__fadd_rn(acc0, acc1), __fadd_rn(acc2, acc3));
}

// selection: numpy-exact fp32 re-score, rank by (value desc, id asc)
__global__ __launch_bounds__(256) void select_kernel(
    const float* __restrict__ Qm, const float* __restrict__ cand,
    const unsigned* __restrict__ idbuf, const int* __restrict__ cnt,
    const int* __restrict__ ident, float* __restrict__ out, int N, int B, int cap) {
    __shared__ unsigned long long skey[CAP_MAX];
    __shared__ float qrow[D_DIM];
    int q = blockIdx.x;
    for (int i = threadIdx.x; i < D_DIM; i += blockDim.x) qrow[i] = Qm[(size_t)q * D_DIM + i];
    __syncthreads();

    int n = cnt[q]; if (n > cap) n = cap; if (n > CAP_MAX) n = CAP_MAX;
    for (int i = threadIdx.x; i < CAP_MAX; i += blockDim.x) {
        unsigned long long key = 0ULL;
        if (i < n) {
            unsigned id = idbuf[(size_t)q * cap + i];
            if (id < (unsigned)N) {
                float s = np_score(qrow, cand + (size_t)id * D_DIM);
                key = make_key(s, id);
            }
        }
        skey[i] = key;
    }

    bitonic_sort_u64<CAP_MAX>(skey);   // ascending: best at the end

    for (int t = threadIdx.x; t < K_TOP; t += blockDim.x) {
        unsigned long long key = skey[CAP_MAX - 1 - t];
        unsigned vm = (unsigned)(key >> 32);
        unsigned vb = (vm & 0x80000000u) ? (vm ^ 0x80000000u) : ~vm;
        unsigned id = 0xFFFFFFFFu - (unsigned)(key & 0xFFFFFFFFu);
        if (id >= (unsigned)N) id = 0;  // unreachable pad guard
        out[(size_t)q * K_TOP + t] = __uint_as_float(vb);
        out[(size_t)B * K_TOP + (size_t)q * K_TOP + t] = (float)ident[id];
    }
}

extern "C" void kernel_launch(void* const* d_in, const int* in_sizes, int n_in,
                              void* d_out, int out_size, void* d_ws, size_t ws_size,
                              hipStream_t stream) {
    const float* queries = (const float*)d_in[0];
    const float* cands   = (const float*)d_in[1];
    const int*   ident   = (const int*)d_in[2];
    const int B = in_sizes[0] / D_DIM;   // 512
    const int N = in_sizes[2];           // 500000
    float* out = (float*)d_out;

    // ws layout: cnt (2KB) | thr (2KB) | qb16 (B*128*2 = 128KB) | idbuf
    char* ws = (char*)d_ws;
    int*   cnt = (int*)ws;
    float* thr = (float*)(ws + 2048);
    unsigned short* qb16 = (unsigned short*)(ws + 4096);
    size_t ids_off = 4096 + (size_t)B * D_DIM * 2;
    unsigned* idbuf = (unsigned*)(ws + ids_off);
    int cap = CAP_MAX;
    if (ws_size > ids_off) {
        size_t fit = (ws_size - ids_off) / ((size_t)B * 4);
        if (fit < (size_t)cap) cap = (int)fit;
    } else cap = 1;
    if (cap < 1) cap = 1;

    prep2_kernel<<<(B + 255) / 256, 256, 0, stream>>>(queries, thr, cnt, qb16, B);

    int gx = (N + 127) / 128;
    mfma_filter_kernel<<<gx, 256, 0, stream>>>(cands, qb16, thr, idbuf, cnt, N, B, cap);

    fallback_kernel<<<B, 256, 0, stream>>>(queries, cands, idbuf, cnt, N, cap);

    select_kernel<<<B, 256, 0, stream>>>(queries, cands, idbuf, cnt, ident, out, N, B, cap);
}

// Round 9
// 316.495 us; speedup vs baseline: 388.2360x; 1.0604x over previous
//
#include <hip/hip_runtime.h>
#include <cfloat>

// BruteForce top-K: B=512 x N=500000, D=128 fp32, K=100.
// (1) bf16 MFMA scoring: candidate tile in LDS (XOR-swizzled, staged once,
//     fp32->bf16 in-register); query B-fragments PRE-ARRANGED in fragment
//     order in ws, loaded global->VGPR (L2-hot, coalesced) -- NO barriers in
//     the main loop. Fused statistical filter t_q = 3.25*|q| (~289
//     survivors/query; bf16 noise ~0.03 << 3.3 margin -> superset w.p. ~1).
// (2) fallback (only if cnt<K or cnt>cap): exact fp32 rescan, top-min(cap,256).
// (3) select: numpy-bit-exact fp32 re-score of survivors (SSE-baseline
//     emulation), rank by (value desc, id asc). Exact output.

#define D_DIM 128
#define K_TOP 100
#define THRESH_SIGMA 3.25f
#define CAP_MAX 1024
#define KEEP_MAXF 256

typedef short bf16x8 __attribute__((ext_vector_type(8)));
typedef float f32x4 __attribute__((ext_vector_type(4)));

__device__ __forceinline__ unsigned short f2bf(float x) {  // RNE fp32->bf16
    unsigned u = __float_as_uint(x);
    return (unsigned short)((u + 0x7FFFu + ((u >> 16) & 1u)) >> 16);
}

__device__ __forceinline__ unsigned long long make_key(float v, unsigned id) {
    unsigned vb = __float_as_uint(v);
    unsigned vm = (vb & 0x80000000u) ? ~vb : (vb | 0x80000000u);  // monotone map
    return ((unsigned long long)vm << 32) | (0xFFFFFFFFu - id);   // val asc; id asc on tie
}

template <int S>
__device__ inline void bitonic_sort_u64(unsigned long long* buf) {
    for (int k = 2; k <= S; k <<= 1) {
        for (int j = k >> 1; j > 0; j >>= 1) {
            __syncthreads();
            for (int i = threadIdx.x; i < S; i += blockDim.x) {
                int l = i ^ j;
                if (l > i) {
                    unsigned long long a = buf[i], b = buf[l];
                    bool sw = ((i & k) == 0) ? (a > b) : (a < b);
                    if (sw) { buf[i] = b; buf[l] = a; }
                }
            }
        }
    }
    __syncthreads();
}

// threshold + counter zero
__global__ void prep2_kernel(const float* __restrict__ Qm, float* __restrict__ thr,
                             int* __restrict__ cnt, int B) {
    int b = blockIdx.x * blockDim.x + threadIdx.x;
    if (b >= B) return;
    float s = 0.f;
    for (int d = 0; d < D_DIM; ++d) { float v = Qm[(size_t)b * D_DIM + d]; s = fmaf(v, v, s); }
    thr[b] = THRESH_SIGMA * sqrtf(s);
    cnt[b] = 0;
}

// build query B-fragments in MFMA order: qf[((qch*8+qb)*4+ks)*64 + l] =
// 8 bf16 of Q[qch*128+qb*16+(l&15)][ks*32+(l>>4)*8 .. +8]
__global__ void qfrag_kernel(const float* __restrict__ Qm, uint4* __restrict__ qf,
                             int B, int nch) {
    int tid = blockIdx.x * blockDim.x + threadIdx.x;
    int total = nch * 8 * 4 * 64;
    if (tid >= total) return;
    int l  = tid & 63;
    int ks = (tid >> 6) & 3;
    int qb = (tid >> 8) & 7;
    int qch = tid >> 11;
    int qrow = qch * 128 + qb * 16 + (l & 15);
    int k0 = ks * 32 + (l >> 4) * 8;
    uint4 o = make_uint4(0u, 0u, 0u, 0u);
    if (qrow < B) {
        const float* src = Qm + (size_t)qrow * D_DIM + k0;
        unsigned r[4];
#pragma unroll
        for (int j = 0; j < 4; ++j)
            r[j] = (unsigned)f2bf(src[2 * j]) | ((unsigned)f2bf(src[2 * j + 1]) << 16);
        o = make_uint4(r[0], r[1], r[2], r[3]);
    }
    qf[tid] = o;
}

// bf16 MFMA + threshold filter. 4 waves; 128 cands/block (LDS tile, XOR
// swizzle); loops nch query chunks of 128; B-frags direct from global.
template <int NCH_CT>
__global__ __launch_bounds__(256) void mfma_filter_kernel(
    const float* __restrict__ cand, const bf16x8* __restrict__ qfrag,
    const float* __restrict__ thr, unsigned* __restrict__ idbuf,
    int* __restrict__ cnt, int N, int B, int cap, int nch_rt) {
    __shared__ char cl[32768];
    const int t = threadIdx.x;
    const int w = t >> 6;
    const int l = t & 63;
    const int c0 = blockIdx.x * 128;
    const int nch = (NCH_CT > 0) ? NCH_CT : nch_rt;

    // stage candidate tile: 128 rows x 128 f32 -> bf16, swizzled
#pragma unroll
    for (int i = 0; i < 16; ++i) {
        int f4 = i * 256 + t;        // flat float4 index, 4096 total
        int row = f4 >> 5;           // 32 float4 per row
        int colf4 = f4 & 31;
        int gc = c0 + row;
        float4 v = make_float4(0.f, 0.f, 0.f, 0.f);
        if (gc < N) v = *reinterpret_cast<const float4*>(cand + (size_t)gc * D_DIM + colf4 * 4);
        uint2 pk;
        pk.x = (unsigned)f2bf(v.x) | ((unsigned)f2bf(v.y) << 16);
        pk.y = (unsigned)f2bf(v.z) | ((unsigned)f2bf(v.w) << 16);
        int byte = row * 256 + ((colf4 * 8) ^ ((row & 7) << 4));
        *reinterpret_cast<uint2*>(cl + byte) = pk;
    }
    __syncthreads();

    // A fragments (cands) once: af[cb][ks]
    bf16x8 af[2][4];
#pragma unroll
    for (int cb = 0; cb < 2; ++cb) {
        int row = w * 32 + cb * 16 + (l & 15);
        int sw = (row & 7) << 4;
#pragma unroll
        for (int ks = 0; ks < 4; ++ks) {
            int byte = row * 256 + ((ks * 64 + ((l >> 4) * 16)) ^ sw);
            af[cb][ks] = *reinterpret_cast<const bf16x8*>(cl + byte);
        }
    }

#pragma unroll
    for (int qch = 0; qch < nch; ++qch) {
        const bf16x8* base = qfrag + (size_t)qch * 2048;   // 8*4*64 frags/chunk

        f32x4 acc[2][8];
#pragma unroll
        for (int cb = 0; cb < 2; ++cb)
#pragma unroll
            for (int qb = 0; qb < 8; ++qb) acc[cb][qb] = (f32x4){0.f, 0.f, 0.f, 0.f};

#pragma unroll
        for (int qb = 0; qb < 8; ++qb) {
            bf16x8 bq[4];
#pragma unroll
            for (int ks = 0; ks < 4; ++ks) bq[ks] = base[(qb * 4 + ks) * 64 + l];
#pragma unroll
            for (int cb = 0; cb < 2; ++cb)
#pragma unroll
                for (int ks = 0; ks < 4; ++ks)
                    acc[cb][qb] = __builtin_amdgcn_mfma_f32_16x16x32_bf16(
                        af[cb][ks], bq[ks], acc[cb][qb], 0, 0, 0);
        }

        // filter epilogue: fast-reject via max tree; D: col=lane&15 (query),
        // row=(lane>>4)*4+reg (cand)
#pragma unroll
        for (int qb = 0; qb < 8; ++qb) {
            int qg = qch * 128 + qb * 16 + (l & 15);
            if (qg >= B) continue;
            float tv = thr[qg];
#pragma unroll
            for (int cb = 0; cb < 2; ++cb) {
                f32x4 a = acc[cb][qb];
                float m = fmaxf(fmaxf(a[0], a[1]), fmaxf(a[2], a[3]));
                if (m > tv) {
#pragma unroll
                    for (int r = 0; r < 4; ++r) {
                        if (a[r] > tv) {
                            int cid = c0 + w * 32 + cb * 16 + ((l >> 4) << 2) + r;
                            if (cid < N) {
                                int pos = atomicAdd(&cnt[qg], 1);
                                if (pos < cap) idbuf[(size_t)qg * cap + pos] = (unsigned)cid;
                            }
                        }
                    }
                }
            }
        }
    }
}

// exact fallback: keeps top-keep (keep = min(cap,256)) by fp32
__global__ void fallback_kernel(const float* __restrict__ Qm, const float* __restrict__ cand,
                                unsigned* __restrict__ idbuf, int* __restrict__ cnt,
                                int N, int cap) {
    int q = blockIdx.x;
    int c0 = cnt[q];
    if (c0 >= K_TOP && c0 <= cap) return;
    int keep = (cap < KEEP_MAXF) ? cap : KEEP_MAXF;

    __shared__ unsigned long long buf[2048];
    __shared__ float qrow[D_DIM];
    __shared__ int bn;
    __shared__ float theta;
    __shared__ int validn;
    for (int i = threadIdx.x; i < D_DIM; i += blockDim.x) qrow[i] = Qm[(size_t)q * D_DIM + i];
    for (int i = threadIdx.x; i < 2048; i += blockDim.x) buf[i] = 0ULL;
    if (threadIdx.x == 0) { bn = 0; theta = -3.0e38f; }
    __syncthreads();

    for (int base = 0; base < N; base += blockDim.x) {
        int c = base + threadIdx.x;
        if (c < N) {
            float s = 0.f;
            for (int d = 0; d < D_DIM; ++d) s = fmaf(qrow[d], cand[(size_t)c * D_DIM + d], s);
            if (s > theta) {
                int p = atomicAdd(&bn, 1);
                if (p < 2048) buf[p] = make_key(s, (unsigned)c);
            }
        }
        __syncthreads();
        if (bn > 2048 - 256 - 8) {  // compress: keep top-keep, raise theta
            bitonic_sort_u64<2048>(buf);
            unsigned long long kv = (threadIdx.x < (unsigned)keep) ? buf[2047 - threadIdx.x] : 0ULL;
            __syncthreads();
            for (int i = threadIdx.x; i < 2048; i += blockDim.x) buf[i] = 0ULL;
            __syncthreads();
            if (threadIdx.x < (unsigned)keep) buf[threadIdx.x] = kv;
            if ((int)threadIdx.x == keep - 1) {
                unsigned vm = (unsigned)(kv >> 32);
                unsigned vb = (vm & 0x80000000u) ? (vm ^ 0x80000000u) : ~vm;
                theta = __uint_as_float(vb) - 0.01f;
            }
            if (threadIdx.x == 0) bn = keep;
            __syncthreads();
        }
    }
    bitonic_sort_u64<2048>(buf);
    if (threadIdx.x == 0) validn = 0;
    __syncthreads();
    unsigned long long kv = (threadIdx.x < (unsigned)keep) ? buf[2047 - threadIdx.x] : 0ULL;
    if (kv != 0ULL) atomicAdd(&validn, 1);
    __syncthreads();
    if ((int)threadIdx.x < validn && threadIdx.x < (unsigned)keep) {
        unsigned id = 0xFFFFFFFFu - (unsigned)(kv & 0xFFFFFFFFu);
        if (id < (unsigned)N) idbuf[(size_t)q * cap + threadIdx.x] = id;
    }
    if (threadIdx.x == 0) cnt[q] = (validn < keep) ? validn : keep;
}

// --- bit-exact emulation of numpy einsum fp32 dot (SSE baseline, no FMA) ---
__device__ __forceinline__ float np_lane_chain(float q0, float b0v, float q1, float b1v,
                                               float q2, float b2v, float q3, float b3v,
                                               float acc) {
    float t = __fadd_rn(__fmul_rn(q3, b3v), acc);
    t = __fadd_rn(__fmul_rn(q2, b2v), t);
    t = __fadd_rn(__fmul_rn(q1, b1v), t);
    return __fadd_rn(__fmul_rn(q0, b0v), t);
}

__device__ __forceinline__ float np_score(const float* __restrict__ qrow,
                                          const float* __restrict__ crow) {
    float acc0 = 0.f, acc1 = 0.f, acc2 = 0.f, acc3 = 0.f;
#pragma unroll
    for (int d0 = 0; d0 < D_DIM; d0 += 16) {
        float4 b0 = *reinterpret_cast<const float4*>(crow + d0 + 0);
        float4 b1 = *reinterpret_cast<const float4*>(crow + d0 + 4);
        float4 b2 = *reinterpret_cast<const float4*>(crow + d0 + 8);
        float4 b3 = *reinterpret_cast<const float4*>(crow + d0 + 12);
        acc0 = np_lane_chain(qrow[d0 + 0], b0.x, qrow[d0 + 4], b1.x,
                             qrow[d0 + 8], b2.x, qrow[d0 + 12], b3.x, acc0);
        acc1 = np_lane_chain(qrow[d0 + 1], b0.y, qrow[d0 + 5], b1.y,
                             qrow[d0 + 9], b2.y, qrow[d0 + 13], b3.y, acc1);
        acc2 = np_lane_chain(qrow[d0 + 2], b0.z, qrow[d0 + 6], b1.z,
                             qrow[d0 + 10], b2.z, qrow[d0 + 14], b3.z, acc2);
        acc3 = np_lane_chain(qrow[d0 + 3], b0.w, qrow[d0 + 7], b1.w,
                             qrow[d0 + 11], b2.w, qrow[d0 + 15], b3.w, acc3);
    }
    return __fadd_rn(__fadd_rn(acc0, acc1), __fadd_rn(acc2, acc3));
}

// selection: numpy-exact fp32 re-score, rank by (value desc, id asc)
__global__ __launch_bounds__(256) void select_kernel(
    const float* __restrict__ Qm, const float* __restrict__ cand,
    const unsigned* __restrict__ idbuf, const int* __restrict__ cnt,
    const int* __restrict__ ident, float* __restrict__ out, int N, int B, int cap) {
    __shared__ unsigned long long skey[CAP_MAX];
    __shared__ float qrow[D_DIM];
    int q = blockIdx.x;
    for (int i = threadIdx.x; i < D_DIM; i += blockDim.x) qrow[i] = Qm[(size_t)q * D_DIM + i];
    __syncthreads();

    int n = cnt[q]; if (n > cap) n = cap; if (n > CAP_MAX) n = CAP_MAX;
    for (int i = threadIdx.x; i < CAP_MAX; i += blockDim.x) {
        unsigned long long key = 0ULL;
        if (i < n) {
            unsigned id = idbuf[(size_t)q * cap + i];
            if (id < (unsigned)N) {
                float s = np_score(qrow, cand + (size_t)id * D_DIM);
                key = make_key(s, id);
            }
        }
        skey[i] = key;
    }

    bitonic_sort_u64<CAP_MAX>(skey);   // ascending: best at the end

    for (int t = threadIdx.x; t < K_TOP; t += blockDim.x) {
        unsigned long long key = skey[CAP_MAX - 1 - t];
        unsigned vm = (unsigned)(key >> 32);
        unsigned vb = (vm & 0x80000000u) ? (vm ^ 0x80000000u) : ~vm;
        unsigned id = 0xFFFFFFFFu - (unsigned)(key & 0xFFFFFFFFu);
        if (id >= (unsigned)N) id = 0;  // unreachable pad guard
        out[(size_t)q * K_TOP + t] = __uint_as_float(vb);
        out[(size_t)B * K_TOP + (size_t)q * K_TOP + t] = (float)ident[id];
    }
}

extern "C" void kernel_launch(void* const* d_in, const int* in_sizes, int n_in,
                              void* d_out, int out_size, void* d_ws, size_t ws_size,
                              hipStream_t stream) {
    const float* queries = (const float*)d_in[0];
    const float* cands   = (const float*)d_in[1];
    const int*   ident   = (const int*)d_in[2];
    const int B = in_sizes[0] / D_DIM;   // 512
    const int N = in_sizes[2];           // 500000
    float* out = (float*)d_out;
    const int nch = (B + 127) >> 7;

    // ws layout: cnt (2KB) | thr (2KB) | qfrag (nch*32KB) | idbuf
    char* ws = (char*)d_ws;
    int*   cnt = (int*)ws;
    float* thr = (float*)(ws + 2048);
    uint4* qfrag = (uint4*)(ws + 4096);
    size_t ids_off = 4096 + (size_t)nch * 32768;
    unsigned* idbuf = (unsigned*)(ws + ids_off);
    int cap = CAP_MAX;
    if (ws_size > ids_off) {
        size_t fit = (ws_size - ids_off) / ((size_t)B * 4);
        if (fit < (size_t)cap) cap = (int)fit;
    } else cap = 1;
    if (cap < 1) cap = 1;

    prep2_kernel<<<(B + 255) / 256, 256, 0, stream>>>(queries, thr, cnt, B);
    int qft = nch * 2048;
    qfrag_kernel<<<(qft + 255) / 256, 256, 0, stream>>>(queries, qfrag, B, nch);

    int gx = (N + 127) / 128;
    if (nch == 4)
        mfma_filter_kernel<4><<<gx, 256, 0, stream>>>(
            cands, (const bf16x8*)qfrag, thr, idbuf, cnt, N, B, cap, nch);
    else
        mfma_filter_kernel<0><<<gx, 256, 0, stream>>>(
            cands, (const bf16x8*)qfrag, thr, idbuf, cnt, N, B, cap, nch);

    fallback_kernel<<<B, 256, 0, stream>>>(queries, cands, idbuf, cnt, N, cap);

    select_kernel<<<B, 256, 0, stream>>>(queries, cands, idbuf, cnt, ident, out, N, B, cap);
}

// Round 10
// 213.865 us; speedup vs baseline: 574.5443x; 1.4799x over previous
//
#include <hip/hip_runtime.h>
#include <cfloat>

// BruteForce top-K: B=512 x N=500000, D=128 fp32, K=100.
// (1) bf16 MFMA scoring: candidates -> registers (af, loaded once/block,
//     128B row segments), queries -> LDS (fragment-order bf16, ds_read_b128
//     in main loop; no global loads, no long-latency chains). Block = 8
//     waves x 32 cands = 256-cand tile; queries staged in 2 halves (64 KB).
//     Fused filter t_q = 3.25*|q| (~289 survivors/query; bf16 noise ~0.03
//     << 3.3 margin -> survivor superset w.p. ~1).
// (2) fallback (only if cnt<K or cnt>cap): exact fp32 rescan, top-min(cap,256).
// (3) select: numpy-bit-exact fp32 re-score of survivors, rank by
//     (value desc, id asc). Exact output.

#define D_DIM 128
#define K_TOP 100
#define THRESH_SIGMA 3.25f
#define CAP_MAX 1024
#define KEEP_MAXF 256

typedef short bf16x8 __attribute__((ext_vector_type(8)));
typedef float f32x4 __attribute__((ext_vector_type(4)));

__device__ __forceinline__ unsigned short f2bf(float x) {  // RNE fp32->bf16
    unsigned u = __float_as_uint(x);
    return (unsigned short)((u + 0x7FFFu + ((u >> 16) & 1u)) >> 16);
}

__device__ __forceinline__ unsigned long long make_key(float v, unsigned id) {
    unsigned vb = __float_as_uint(v);
    unsigned vm = (vb & 0x80000000u) ? ~vb : (vb | 0x80000000u);  // monotone map
    return ((unsigned long long)vm << 32) | (0xFFFFFFFFu - id);   // val asc; id asc on tie
}

template <int S>
__device__ inline void bitonic_sort_u64(unsigned long long* buf) {
    for (int k = 2; k <= S; k <<= 1) {
        for (int j = k >> 1; j > 0; j >>= 1) {
            __syncthreads();
            for (int i = threadIdx.x; i < S; i += blockDim.x) {
                int l = i ^ j;
                if (l > i) {
                    unsigned long long a = buf[i], b = buf[l];
                    bool sw = ((i & k) == 0) ? (a > b) : (a < b);
                    if (sw) { buf[i] = b; buf[l] = a; }
                }
            }
        }
    }
    __syncthreads();
}

// threshold + counter zero
__global__ void prep2_kernel(const float* __restrict__ Qm, float* __restrict__ thr,
                             int* __restrict__ cnt, int B) {
    int b = blockIdx.x * blockDim.x + threadIdx.x;
    if (b >= B) return;
    float s = 0.f;
    for (int d = 0; d < D_DIM; ++d) { float v = Qm[(size_t)b * D_DIM + d]; s = fmaf(v, v, s); }
    thr[b] = THRESH_SIGMA * sqrtf(s);
    cnt[b] = 0;
}

// build query B-fragments in MFMA order: qf[((qch*8+qb)*4+ks)*64 + l] =
// 8 bf16 of Q[qch*128+qb*16+(l&15)][ks*32+(l>>4)*8 .. +8]
__global__ void qfrag_kernel(const float* __restrict__ Qm, uint4* __restrict__ qf,
                             int B, int nch) {
    int tid = blockIdx.x * blockDim.x + threadIdx.x;
    int total = nch * 8 * 4 * 64;
    if (tid >= total) return;
    int l  = tid & 63;
    int ks = (tid >> 6) & 3;
    int qb = (tid >> 8) & 7;
    int qch = tid >> 11;
    int qrow = qch * 128 + qb * 16 + (l & 15);
    int k0 = ks * 32 + (l >> 4) * 8;
    uint4 o = make_uint4(0u, 0u, 0u, 0u);
    if (qrow < B) {
        const float* src = Qm + (size_t)qrow * D_DIM + k0;
        unsigned r[4];
#pragma unroll
        for (int j = 0; j < 4; ++j)
            r[j] = (unsigned)f2bf(src[2 * j]) | ((unsigned)f2bf(src[2 * j + 1]) << 16);
        o = make_uint4(r[0], r[1], r[2], r[3]);
    }
    qf[tid] = o;
}

// bf16 MFMA + filter. 512 thr = 8 waves; 256-cand tile; candidates in regs,
// queries in LDS (staged per 128-query chunk pair), thr in LDS.
template <int NCH_CT>
__global__ __launch_bounds__(512) void mfma_filter_kernel(
    const float* __restrict__ cand, const uint4* __restrict__ qfrag,
    const float* __restrict__ thr, unsigned* __restrict__ idbuf,
    int* __restrict__ cnt, int N, int B, int cap, int nch_rt) {
    __shared__ uint4 ql[4096];       // 64 KB: 2 chunks x 128 queries, frag order
    __shared__ float tl[512];        // thresholds
    const int t = threadIdx.x;
    const int w = t >> 6;            // wave 0..7
    const int l = t & 63;
    const int c0 = blockIdx.x * 256;
    const int nch = (NCH_CT > 0) ? NCH_CT : nch_rt;

    if (t < B && t < 512) tl[t] = thr[t];

    // A fragments: wave w owns cands c0 + w*32 .. +31 (clamped; guarded at push)
    bf16x8 af[2][4];
#pragma unroll
    for (int cb = 0; cb < 2; ++cb) {
        int grow = c0 + w * 32 + cb * 16 + (l & 15);
        if (grow > N - 1) grow = N - 1;
        const float* src = cand + (size_t)grow * D_DIM;
#pragma unroll
        for (int ks = 0; ks < 4; ++ks) {
            int k0 = ks * 32 + (l >> 4) * 8;
            float4 a = *reinterpret_cast<const float4*>(src + k0);
            float4 b = *reinterpret_cast<const float4*>(src + k0 + 4);
            union { bf16x8 v; unsigned u[4]; } p;
            p.u[0] = (unsigned)f2bf(a.x) | ((unsigned)f2bf(a.y) << 16);
            p.u[1] = (unsigned)f2bf(a.z) | ((unsigned)f2bf(a.w) << 16);
            p.u[2] = (unsigned)f2bf(b.x) | ((unsigned)f2bf(b.y) << 16);
            p.u[3] = (unsigned)f2bf(b.z) | ((unsigned)f2bf(b.w) << 16);
            af[cb][ks] = p.v;
        }
    }

    const int nhalf = (nch + 1) >> 1;
#pragma unroll 1
    for (int h = 0; h < nhalf; ++h) {
        __syncthreads();             // previous half's reads done
        int ch0 = h * 2;
        int nstage = nch - ch0; if (nstage > 2) nstage = 2;
        for (int i = t; i < nstage * 2048; i += 512)
            ql[i] = qfrag[(size_t)ch0 * 2048 + i];
        __syncthreads();

#pragma unroll 1
        for (int cc = 0; cc < nstage; ++cc) {
#pragma unroll
            for (int qb = 0; qb < 8; ++qb) {
                bf16x8 bq[4];
#pragma unroll
                for (int ks = 0; ks < 4; ++ks) {
                    int fi = (cc * 8 + qb) * 4 + ks;
                    bq[ks] = *reinterpret_cast<const bf16x8*>(
                        reinterpret_cast<const char*>(ql) + fi * 1024 + l * 16);
                }
                f32x4 acc0 = (f32x4){0.f, 0.f, 0.f, 0.f};
                f32x4 acc1 = (f32x4){0.f, 0.f, 0.f, 0.f};
#pragma unroll
                for (int ks = 0; ks < 4; ++ks) {
                    acc0 = __builtin_amdgcn_mfma_f32_16x16x32_bf16(af[0][ks], bq[ks], acc0, 0, 0, 0);
                    acc1 = __builtin_amdgcn_mfma_f32_16x16x32_bf16(af[1][ks], bq[ks], acc1, 0, 0, 0);
                }
                int qg = (ch0 + cc) * 128 + qb * 16 + (l & 15);
                if (qg >= B) continue;
                float tv = tl[qg & 511];
                // epilogue: D col=lane&15 (query), row=(lane>>4)*4+reg (cand)
#pragma unroll
                for (int cb = 0; cb < 2; ++cb) {
                    f32x4 a = (cb == 0) ? acc0 : acc1;
                    float m = fmaxf(fmaxf(a[0], a[1]), fmaxf(a[2], a[3]));
                    if (m > tv) {
#pragma unroll
                        for (int r = 0; r < 4; ++r) {
                            if (a[r] > tv) {
                                int cid = c0 + w * 32 + cb * 16 + ((l >> 4) << 2) + r;
                                if (cid < N) {
                                    int pos = atomicAdd(&cnt[qg], 1);
                                    if (pos < cap) idbuf[(size_t)qg * cap + pos] = (unsigned)cid;
                                }
                            }
                        }
                    }
                }
            }
        }
    }
}

// exact fallback: keeps top-keep (keep = min(cap,256)) by fp32
__global__ void fallback_kernel(const float* __restrict__ Qm, const float* __restrict__ cand,
                                unsigned* __restrict__ idbuf, int* __restrict__ cnt,
                                int N, int cap) {
    int q = blockIdx.x;
    int c0 = cnt[q];
    if (c0 >= K_TOP && c0 <= cap) return;
    int keep = (cap < KEEP_MAXF) ? cap : KEEP_MAXF;

    __shared__ unsigned long long buf[2048];
    __shared__ float qrow[D_DIM];
    __shared__ int bn;
    __shared__ float theta;
    __shared__ int validn;
    for (int i = threadIdx.x; i < D_DIM; i += blockDim.x) qrow[i] = Qm[(size_t)q * D_DIM + i];
    for (int i = threadIdx.x; i < 2048; i += blockDim.x) buf[i] = 0ULL;
    if (threadIdx.x == 0) { bn = 0; theta = -3.0e38f; }
    __syncthreads();

    for (int base = 0; base < N; base += blockDim.x) {
        int c = base + threadIdx.x;
        if (c < N) {
            float s = 0.f;
            for (int d = 0; d < D_DIM; ++d) s = fmaf(qrow[d], cand[(size_t)c * D_DIM + d], s);
            if (s > theta) {
                int p = atomicAdd(&bn, 1);
                if (p < 2048) buf[p] = make_key(s, (unsigned)c);
            }
        }
        __syncthreads();
        if (bn > 2048 - 256 - 8) {  // compress: keep top-keep, raise theta
            bitonic_sort_u64<2048>(buf);
            unsigned long long kv = (threadIdx.x < (unsigned)keep) ? buf[2047 - threadIdx.x] : 0ULL;
            __syncthreads();
            for (int i = threadIdx.x; i < 2048; i += blockDim.x) buf[i] = 0ULL;
            __syncthreads();
            if (threadIdx.x < (unsigned)keep) buf[threadIdx.x] = kv;
            if ((int)threadIdx.x == keep - 1) {
                unsigned vm = (unsigned)(kv >> 32);
                unsigned vb = (vm & 0x80000000u) ? (vm ^ 0x80000000u) : ~vm;
                theta = __uint_as_float(vb) - 0.01f;
            }
            if (threadIdx.x == 0) bn = keep;
            __syncthreads();
        }
    }
    bitonic_sort_u64<2048>(buf);
    if (threadIdx.x == 0) validn = 0;
    __syncthreads();
    unsigned long long kv = (threadIdx.x < (unsigned)keep) ? buf[2047 - threadIdx.x] : 0ULL;
    if (kv != 0ULL) atomicAdd(&validn, 1);
    __syncthreads();
    if ((int)threadIdx.x < validn && threadIdx.x < (unsigned)keep) {
        unsigned id = 0xFFFFFFFFu - (unsigned)(kv & 0xFFFFFFFFu);
        if (id < (unsigned)N) idbuf[(size_t)q * cap + threadIdx.x] = id;
    }
    if (threadIdx.x == 0) cnt[q] = (validn < keep) ? validn : keep;
}

// --- bit-exact emulation of numpy einsum fp32 dot (SSE baseline, no FMA) ---
__device__ __forceinline__ float np_lane_chain(float q0, float b0v, float q1, float b1v,
                                               float q2, float b2v, float q3, float b3v,
                                               float acc) {
    float t = __fadd_rn(__fmul_rn(q3, b3v), acc);
    t = __fadd_rn(__fmul_rn(q2, b2v), t);
    t = __fadd_rn(__fmul_rn(q1, b1v), t);
    return __fadd_rn(__fmul_rn(q0, b0v), t);
}

__device__ __forceinline__ float np_score(const float* __restrict__ qrow,
                                          const float* __restrict__ crow) {
    float acc0 = 0.f, acc1 = 0.f, acc2 = 0.f, acc3 = 0.f;
#pragma unroll
    for (int d0 = 0; d0 < D_DIM; d0 += 16) {
        float4 b0 = *reinterpret_cast<const float4*>(crow + d0 + 0);
        float4 b1 = *reinterpret_cast<const float4*>(crow + d0 + 4);
        float4 b2 = *reinterpret_cast<const float4*>(crow + d0 + 8);
        float4 b3 = *reinterpret_cast<const float4*>(crow + d0 + 12);
        acc0 = np_lane_chain(qrow[d0 + 0], b0.x, qrow[d0 + 4], b1.x,
                             qrow[d0 + 8], b2.x, qrow[d0 + 12], b3.x, acc0);
        acc1 = np_lane_chain(qrow[d0 + 1], b0.y, qrow[d0 + 5], b1.y,
                             qrow[d0 + 9], b2.y, qrow[d0 + 13], b3.y, acc1);
        acc2 = np_lane_chain(qrow[d0 + 2], b0.z, qrow[d0 + 6], b1.z,
                             qrow[d0 + 10], b2.z, qrow[d0 + 14], b3.z, acc2);
        acc3 = np_lane_chain(qrow[d0 + 3], b0.w, qrow[d0 + 7], b1.w,
                             qrow[d0 + 11], b2.w, qrow[d0 + 15], b3.w, acc3);
    }
    return __fadd_rn(__fadd_rn(acc0, acc1), __fadd_rn(acc2, acc3));
}

// selection: numpy-exact fp32 re-score, rank by (value desc, id asc)
__global__ __launch_bounds__(256) void select_kernel(
    const float* __restrict__ Qm, const float* __restrict__ cand,
    const unsigned* __restrict__ idbuf, const int* __restrict__ cnt,
    const int* __restrict__ ident, float* __restrict__ out, int N, int B, int cap) {
    __shared__ unsigned long long skey[CAP_MAX];
    __shared__ float qrow[D_DIM];
    int q = blockIdx.x;
    for (int i = threadIdx.x; i < D_DIM; i += blockDim.x) qrow[i] = Qm[(size_t)q * D_DIM + i];
    __syncthreads();

    int n = cnt[q]; if (n > cap) n = cap; if (n > CAP_MAX) n = CAP_MAX;
    for (int i = threadIdx.x; i < CAP_MAX; i += blockDim.x) {
        unsigned long long key = 0ULL;
        if (i < n) {
            unsigned id = idbuf[(size_t)q * cap + i];
            if (id < (unsigned)N) {
                float s = np_score(qrow, cand + (size_t)id * D_DIM);
                key = make_key(s, id);
            }
        }
        skey[i] = key;
    }

    bitonic_sort_u64<CAP_MAX>(skey);   // ascending: best at the end

    for (int t = threadIdx.x; t < K_TOP; t += blockDim.x) {
        unsigned long long key = skey[CAP_MAX - 1 - t];
        unsigned vm = (unsigned)(key >> 32);
        unsigned vb = (vm & 0x80000000u) ? (vm ^ 0x80000000u) : ~vm;
        unsigned id = 0xFFFFFFFFu - (unsigned)(key & 0xFFFFFFFFu);
        if (id >= (unsigned)N) id = 0;  // unreachable pad guard
        out[(size_t)q * K_TOP + t] = __uint_as_float(vb);
        out[(size_t)B * K_TOP + (size_t)q * K_TOP + t] = (float)ident[id];
    }
}

extern "C" void kernel_launch(void* const* d_in, const int* in_sizes, int n_in,
                              void* d_out, int out_size, void* d_ws, size_t ws_size,
                              hipStream_t stream) {
    const float* queries = (const float*)d_in[0];
    const float* cands   = (const float*)d_in[1];
    const int*   ident   = (const int*)d_in[2];
    const int B = in_sizes[0] / D_DIM;   // 512
    const int N = in_sizes[2];           // 500000
    float* out = (float*)d_out;
    const int nch = (B + 127) >> 7;

    // ws layout: cnt (2KB) | thr (2KB) | qfrag (nch*32KB) | idbuf
    char* ws = (char*)d_ws;
    int*   cnt = (int*)ws;
    float* thr = (float*)(ws + 2048);
    uint4* qfrag = (uint4*)(ws + 4096);
    size_t ids_off = 4096 + (size_t)nch * 32768;
    unsigned* idbuf = (unsigned*)(ws + ids_off);
    int cap = CAP_MAX;
    if (ws_size > ids_off) {
        size_t fit = (ws_size - ids_off) / ((size_t)B * 4);
        if (fit < (size_t)cap) cap = (int)fit;
    } else cap = 1;
    if (cap < 1) cap = 1;

    prep2_kernel<<<(B + 255) / 256, 256, 0, stream>>>(queries, thr, cnt, B);
    int qft = nch * 2048;
    qfrag_kernel<<<(qft + 255) / 256, 256, 0, stream>>>(queries, qfrag, B, nch);

    int gx = (N + 255) / 256;
    if (nch == 4)
        mfma_filter_kernel<4><<<gx, 512, 0, stream>>>(
            cands, qfrag, thr, idbuf, cnt, N, B, cap, nch);
    else
        mfma_filter_kernel<0><<<gx, 512, 0, stream>>>(
            cands, qfrag, thr, idbuf, cnt, N, B, cap, nch);

    fallback_kernel<<<B, 256, 0, stream>>>(queries, cands, idbuf, cnt, N, cap);

    select_kernel<<<B, 256, 0, stream>>>(queries, cands, idbuf, cnt, ident, out, N, B, cap);
}